// Round 10
// baseline (169.216 us; speedup 1.0000x reference)
//
#include <hip/hip_runtime.h>
#include <math.h>

#define NDEG 12

typedef unsigned short u16;
typedef unsigned int u32;
typedef _Float16 f16;
typedef __attribute__((ext_vector_type(8))) _Float16 f16x8;
typedef __attribute__((ext_vector_type(8))) short bf16x8;
typedef __attribute__((ext_vector_type(4))) float f32x4;

#define MFMA_F16(a, b, c)  __builtin_amdgcn_mfma_f32_16x16x32_f16(a, b, c, 0, 0, 0)
#define MFMA_BF16(a, b, c) __builtin_amdgcn_mfma_f32_16x16x32_bf16(a, b, c, 0, 0, 0)

__device__ __forceinline__ u32 fbits(float x) { return __float_as_uint(x); }
__device__ __forceinline__ float fval(u32 u) { return __uint_as_float(u); }
__device__ __forceinline__ f32x4 zero4() {
  f32x4 z; z[0] = 0.f; z[1] = 0.f; z[2] = 0.f; z[3] = 0.f; return z;
}
__device__ __forceinline__ u16 f16bits(f16 x) { u16 u; __builtin_memcpy(&u, &x, 2); return u; }
__device__ __forceinline__ float f16tof(u16 u) { f16 h; __builtin_memcpy(&h, &u, 2); return (float)h; }

// bf16 hi (trunc) + bf16 lo (RNE remainder) split  [rounds 2-8 known-good]
__device__ __forceinline__ void split2(float x, u32& h, u32& l) {
  u32 u = fbits(x);
  h = u >> 16;
  float lo = x - fval(u & 0xFFFF0000u);
  u32 v = fbits(lo);
  l = (v + 0x7FFFu + ((v >> 16) & 1u)) >> 16;
}
__device__ __forceinline__ void writePair(u32* Hw, u32* Lw, int widx, float v, int lane) {
  float pv = __shfl_xor(v, 1);
  u32 hv, lv, hp, lp;
  split2(v, hv, lv);
  split2(pv, hp, lp);
  const bool even = (lane & 1) == 0;
  u32 word = even ? (hv | (hp << 16)) : (lp | (lv << 16));
  u32* base = even ? Hw : Lw;
  base[widx] = word;
}

struct CovPh { char buf[2][32768]; };                    // 2 pair-regions x 2 tiles x [128][64] f16, swizzled
struct ProjPh { u16 Cov[128][136]; u16 Wt[64][136]; };   // 52224 B
struct ChebPh {
  u16 MH[64][72]; u16 ML[64][72];
  u16 TbH[2][64][72]; u16 TbL[2][64][72];
};                                                        // 55296 B
struct RedPh { float red[256][4]; };                      // 4096 B (overlays ChebPh when dead)
union SmemU { CovPh a; ProjPh p; ChebPh c; RedPh r; };
static_assert(sizeof(SmemU) == 65536, "smem");

// 8-wave Gram split: flat upper-tri tile list for row-pair (W, 7-W):
// k=0..7-W: (W, W+k); k=8-W..8: (7-W, 7-W+(k-(8-W))). Wave 2W+H takes parity-H entries.
template <int W, int H>
__device__ __forceinline__ void gram8(const char* bufb, int fo0, int fo1,
                                      f32x4 (&acc)[5], f32x4& xs, f16x8 ones) {
  constexpr int I2 = 7 - W;
#pragma unroll
  for (int ch = 0; ch < 2; ++ch) {
    const int fo = ch ? fo1 : fo0;
    f16x8 F[8];
#pragma unroll
    for (int J = W; J < 8; ++J)
      F[J] = *(const f16x8*)(bufb + J * 2048 + fo);
#pragma unroll
    for (int k = 0; k < 9; ++k) {
      if ((k & 1) != H) continue;
      const int I = (k <= 7 - W) ? W : I2;
      const int J = (k <= 7 - W) ? (W + k) : (I2 + (k - (8 - W)));
      acc[k >> 1] = MFMA_F16(F[I], F[J], acc[k >> 1]);
    }
    xs = MFMA_F16(F[2 * W + H], ones, xs);
  }
}

__device__ __forceinline__ void covTile(u16* Cov, const f32x4& v, int I, int J,
                                        int l15, int l16, bool mirror) {
#pragma unroll
  for (int r = 0; r < 4; ++r) {
    int row = 16 * I + 4 * l16 + r;
    int col = 16 * J + l15;
    u16 h = f16bits((f16)(v[r] * 1e-3f));
    Cov[row * 136 + col] = h;
    if (mirror) Cov[col * 136 + row] = h;
  }
}

template <int W, int H>
__device__ __forceinline__ void covStore8(u16* Cov, const f32x4 (&acc)[5], int l15, int l16) {
  constexpr int I2 = 7 - W;
#pragma unroll
  for (int k = 0; k < 9; ++k) {
    if ((k & 1) != H) continue;
    const int I = (k <= 7 - W) ? W : I2;
    const int J = (k <= 7 - W) ? (W + k) : (I2 + (k - (8 - W)));
    covTile(Cov, acc[k >> 1], I, J, l15, l16, I != J);
  }
}

__global__ __launch_bounds__(512, 4) void spdnet_fused8_kernel(
    const float* __restrict__ X, const float* __restrict__ W,
    const float* __restrict__ lin_w, const float* __restrict__ lin_b,
    float* __restrict__ out)
{
  __shared__ SmemU sm;
  __shared__ float mwL[64];
  __shared__ float xsL[128];

  const int tid = threadIdx.x;           // 0..511
  const int lane = tid & 63;
  const int wv = tid >> 6;               // 0..7
  const int l15 = lane & 15;
  const int l16 = lane >> 4;             // 0..3
  const int lq = lane & 31;              // 16-B chunk index within a 128-t row span
  const int rhalf = lane >> 5;           // which row of the instr's row-pair
  const int b = blockIdx.x;
  const char* __restrict__ Xbc = (const char*)(X + (size_t)b * 128000u);

  // ================= phase A: Cov = X X^T, f16 MFMA, 8-wave symmetric split =========
  // instr q: rows {16wv+2q, 16wv+2q+1}; lanes 0-31 sweep row's 128 t (512-B run)
  int goff[8], lb[8];
#pragma unroll
  for (int q = 0; q < 8; ++q) {
    const int rq = 16 * wv + 2 * q + rhalf;
    goff[q] = rq * 4000 + lq * 16;                         // byte offset of (row, t=lq*4)
    lb[q] = rq * 128 + ((l15 * 8) ^ ((rq & 7) << 4));      // within-tile f16 byte addr
  }
  const int tb = (lq >> 4) * 16384;                        // even/odd 64-t tile of the pair
  const int swz = (l15 & 7) << 4;
  const int fo0 = l15 * 128 + ((16 * l16) ^ swz);
  const int fo1 = l15 * 128 + ((16 * l16 + 64) ^ swz);

  f16x8 ones;
#pragma unroll
  for (int i = 0; i < 8; ++i) ones[i] = (f16)1.0f;

  f32x4 acc[5];
#pragma unroll
  for (int u = 0; u < 5; ++u) acc[u] = zero4();
  f32x4 xs = zero4();

  // two STATICALLY-NAMED register pair-buffers (8 float4 each; static idx only)
  float4 ldA[8], ldB[8];

#define L16(ld, pr)                                               \
  do {                                                            \
    _Pragma("unroll")                                             \
    for (int q = 0; q < 8; ++q)                                   \
      ld[q] = *(const float4*)(Xbc + goff[q] + (pr) * 512);       \
  } while (0)
#define L16_TAIL(ld)                                              \
  do {                                                            \
    const bool valid = lq < 26;                                   \
    const int off = valid ? 3584 : (3984 - lq * 16);              \
    _Pragma("unroll")                                             \
    for (int q = 0; q < 8; ++q) {                                 \
      float4 v = *(const float4*)(Xbc + goff[q] + off);           \
      ld[q] = valid ? v : make_float4(0.f, 0.f, 0.f, 0.f);        \
    }                                                             \
  } while (0)
#define SPAIR(bi, ld)                                             \
  do {                                                            \
    char* rb_ = sm.a.buf[bi] + tb;                                \
    _Pragma("unroll")                                             \
    for (int q = 0; q < 8; ++q) {                                 \
      u32 w0 = (u32)f16bits((f16)ld[q].x) | ((u32)f16bits((f16)ld[q].y) << 16); \
      u32 w1 = (u32)f16bits((f16)ld[q].z) | ((u32)f16bits((f16)ld[q].w) << 16); \
      uint2 wr; wr.x = w0; wr.y = w1;                             \
      *(uint2*)(rb_ + lb[q]) = wr;                                \
    }                                                             \
  } while (0)

  auto GRAM2 = [&](const char* rb) {
    switch (wv) {
      case 0: gram8<0,0>(rb, fo0, fo1, acc, xs, ones); gram8<0,0>(rb + 16384, fo0, fo1, acc, xs, ones); break;
      case 1: gram8<0,1>(rb, fo0, fo1, acc, xs, ones); gram8<0,1>(rb + 16384, fo0, fo1, acc, xs, ones); break;
      case 2: gram8<1,0>(rb, fo0, fo1, acc, xs, ones); gram8<1,0>(rb + 16384, fo0, fo1, acc, xs, ones); break;
      case 3: gram8<1,1>(rb, fo0, fo1, acc, xs, ones); gram8<1,1>(rb + 16384, fo0, fo1, acc, xs, ones); break;
      case 4: gram8<2,0>(rb, fo0, fo1, acc, xs, ones); gram8<2,0>(rb + 16384, fo0, fo1, acc, xs, ones); break;
      case 5: gram8<2,1>(rb, fo0, fo1, acc, xs, ones); gram8<2,1>(rb + 16384, fo0, fo1, acc, xs, ones); break;
      case 6: gram8<3,0>(rb, fo0, fo1, acc, xs, ones); gram8<3,0>(rb + 16384, fo0, fo1, acc, xs, ones); break;
      default: gram8<3,1>(rb, fo0, fo1, acc, xs, ones); gram8<3,1>(rb + 16384, fo0, fo1, acc, xs, ones); break;
    }
  };

  // prologue: pairs 0 (ldA), 1 (ldB) issued; counted wait -> pair 0 ready; stage it
  L16(ldA, 0);
  L16(ldB, 1);
  asm volatile("s_waitcnt vmcnt(8)" ::: "memory");
  SPAIR(0, ldA);
  asm volatile("s_waitcnt lgkmcnt(0)" ::: "memory");
  __builtin_amdgcn_s_barrier();

  // depth-2 pipeline; pair k in ldA if k even, ldB if odd; lds[k&1] holds pair k.
  // vmcnt(8) = next pair's 8 loads stay in flight across the barrier (never drain
  // except at the tail).
  for (int h = 0; h < 4; ++h) {
    // ---- even body: pair 2h ----
    if (h < 3) L16(ldA, 2 * h + 2);
    GRAM2(sm.a.buf[0]);
    if (h < 3) asm volatile("s_waitcnt vmcnt(8)" ::: "memory");
    else       asm volatile("s_waitcnt vmcnt(0)" ::: "memory");
    SPAIR(1, ldB);                       // stage pair 2h+1
    asm volatile("s_waitcnt lgkmcnt(0)" ::: "memory");
    __builtin_amdgcn_s_barrier();
    // ---- odd body: pair 2h+1 ----
    if (h < 2) L16(ldB, 2 * h + 3);
    else if (h == 2) L16_TAIL(ldB);      // pair 7
    GRAM2(sm.a.buf[1]);
    if (h < 3) {
      asm volatile("s_waitcnt vmcnt(8)" ::: "memory");
      SPAIR(0, ldA);                     // stage pair 2h+2
      asm volatile("s_waitcnt lgkmcnt(0)" ::: "memory");
      __builtin_amdgcn_s_barrier();
    }
  }
#undef L16
#undef L16_TAIL
#undef SPAIR

  // row sums from ones-MFMA (cols duplicated -> l15==0 lanes)
  if (l15 == 0) {
#pragma unroll
    for (int r = 0; r < 4; ++r) xsL[16 * wv + 4 * l16 + r] = xs[r];
  }
  __syncthreads();   // phase-A LDS reads done -> overlay allowed

  // ================= phase P: materialize Cov (f16, *1e-3) + Wt =================
  {
    u16* CovP = &sm.p.Cov[0][0];
    switch (wv) {
      case 0: covStore8<0,0>(CovP, acc, l15, l16); break;
      case 1: covStore8<0,1>(CovP, acc, l15, l16); break;
      case 2: covStore8<1,0>(CovP, acc, l15, l16); break;
      case 3: covStore8<1,1>(CovP, acc, l15, l16); break;
      case 4: covStore8<2,0>(CovP, acc, l15, l16); break;
      case 5: covStore8<2,1>(CovP, acc, l15, l16); break;
      case 6: covStore8<3,0>(CovP, acc, l15, l16); break;
      default: covStore8<3,1>(CovP, acc, l15, l16); break;
    }
    u16* WtP = &sm.p.Wt[0][0];
    const int c = tid & 127, dh = tid >> 7;               // dh 0..3
    const float4* wp = (const float4*)(W + c * 64 + 16 * dh);
#pragma unroll
    for (int q = 0; q < 4; ++q) {
      float4 v = wp[q];
      int d0 = 16 * dh + 4 * q;
      WtP[(d0    ) * 136 + c] = f16bits((f16)v.x);
      WtP[(d0 + 1) * 136 + c] = f16bits((f16)v.y);
      WtP[(d0 + 2) * 136 + c] = f16bits((f16)v.z);
      WtP[(d0 + 3) * 136 + c] = f16bits((f16)v.w);
    }
  }
  __syncthreads();

  // mw = W^T xsum * 1e-3 (first 64 threads; overlaps P MFMA elsewhere)
  if (tid < 64) {
    float s = 0.f;
    for (int c = 0; c < 128; ++c)
      s = fmaf(f16tof(sm.p.Wt[tid][c]), xsL[c], s);
    mwL[tid] = s * 1.0e-3f;
  }

  // ---- P = Cov * W  (fp16 MFMA; wave wv owns rows 16wv..16wv+16) ----
  const u16* CovP = &sm.p.Cov[0][0];
  const u16* WtP  = &sm.p.Wt[0][0];
  f32x4 pAcc[4];
#pragma unroll
  for (int n = 0; n < 4; ++n) pAcc[n] = zero4();
#pragma unroll
  for (int ch = 0; ch < 4; ++ch) {
    f16x8 aC = *(const f16x8*)&CovP[(16 * wv + l15) * 136 + 8 * l16 + 32 * ch];
#pragma unroll
    for (int n = 0; n < 4; ++n) {
      f16x8 bw = *(const f16x8*)&WtP[(16 * n + l15) * 136 + 8 * l16 + 32 * ch];
      pAcc[n] = MFMA_F16(aC, bw, pAcc[n]);
    }
  }
  __syncthreads();   // Cov reads done -> Pt may overlay

  // ---- Pt[d][c] = P[c][d]  (fp16, overlays Cov) ----
  {
    u16* PtP = (u16*)&sm.p.Cov[0][0];
#pragma unroll
    for (int n = 0; n < 4; ++n)
#pragma unroll
      for (int r = 0; r < 4; ++r) {
        int c = 16 * wv + 4 * l16 + r;
        int d = 16 * n + l15;
        PtP[d * 136 + c] = f16bits((f16)pAcc[n][r]);
      }
  }
  __syncthreads();

  // ---- Y = W^T P  (waves 0..3 own d-rows 16wv..16wv+16) ----
  const u16* PtP = (const u16*)&sm.p.Cov[0][0];
  f32x4 yAcc[4];
#pragma unroll
  for (int n = 0; n < 4; ++n) yAcc[n] = zero4();
  if (wv < 4) {
#pragma unroll
    for (int ch = 0; ch < 4; ++ch) {
      f16x8 aW = *(const f16x8*)&WtP[(16 * wv + l15) * 136 + 8 * l16 + 32 * ch];
#pragma unroll
      for (int n = 0; n < 4; ++n) {
        f16x8 bP = *(const f16x8*)&PtP[(16 * n + l15) * 136 + 8 * l16 + 32 * ch];
        yAcc[n] = MFMA_F16(aW, bP, yAcc[n]);
      }
    }
  }
  __syncthreads();   // Wt/Pt dead -> Chebyshev planes may overlay

  // ================= phase C: M init + Chebyshev matrix-log (bf16 3-term, waves 0-3) ======
  const float CC = 1.125f;
  const float IH = 1.0f / 0.875f;
  const float uu = 0.875f / 1.125f;
  const float rho = (sqrtf(1.0f - uu * uu) - 1.0f) / uu;   // ~ -0.47759
  const float a0c = logf(CC / (1.0f + rho * rho));
  const float a1c = -2.0f * rho;

  f32x4 zz[4], tp[4], tcu[4];
  if (wv < 4) {
    u32* MHw = (u32*)&sm.c.MH[0][0];
    u32* MLw = (u32*)&sm.c.ML[0][0];
#pragma unroll
    for (int n = 0; n < 4; ++n)
#pragma unroll
      for (int r = 0; r < 4; ++r) {
        int i = 16 * wv + 4 * l16 + r, j = 16 * n + l15;
        float y = yAcc[n][r] - mwL[i] * mwL[j];
        float m = (y - ((i == j) ? CC : 0.f)) * IH;
        float e = (i == j) ? 1.f : 0.f;
        tp[n][r] = e;
        tcu[n][r] = m;
        zz[n][r] = a0c * e + a1c * m;
        writePair(MHw, MLw, i * 36 + (j >> 1), m, lane);
      }
  }
  __syncthreads();

  bf16x8 aMh[2], aMl[2];
  if (wv < 4) {
#pragma unroll
    for (int ch = 0; ch < 2; ++ch) {
      aMh[ch] = *(const bf16x8*)&sm.c.MH[16 * wv + l15][8 * l16 + 32 * ch];
      aMl[ch] = *(const bf16x8*)&sm.c.ML[16 * wv + l15][8 * l16 + 32 * ch];
    }
  }

  float rhok = rho;
  for (int k = 2; k <= NDEG; ++k) {
    rhok *= rho;
    const float ak = (-2.0f / (float)k) * rhok;
    if (wv < 4) {
      const u16 (*srcH)[72] = (k == 2) ? sm.c.MH : sm.c.TbH[(k - 1) & 1];
      const u16 (*srcL)[72] = (k == 2) ? sm.c.ML : sm.c.TbL[(k - 1) & 1];
      f32x4 p[4];
#pragma unroll
      for (int n = 0; n < 4; ++n) p[n] = zero4();
#pragma unroll
      for (int ch = 0; ch < 2; ++ch) {
#pragma unroll
        for (int n = 0; n < 4; ++n) {
          bf16x8 bh = *(const bf16x8*)&srcH[16 * n + l15][8 * l16 + 32 * ch];
          bf16x8 bl = *(const bf16x8*)&srcL[16 * n + l15][8 * l16 + 32 * ch];
          p[n] = MFMA_BF16(aMh[ch], bh, p[n]);
          p[n] = MFMA_BF16(aMh[ch], bl, p[n]);
          p[n] = MFMA_BF16(aMl[ch], bh, p[n]);
        }
      }
      u32* dH = (u32*)&sm.c.TbH[k & 1][0][0];
      u32* dL = (u32*)&sm.c.TbL[k & 1][0][0];
#pragma unroll
      for (int n = 0; n < 4; ++n) {
        f32x4 tn;
#pragma unroll
        for (int r = 0; r < 4; ++r) {
          tn[r] = 2.f * p[n][r] - tp[n][r];
          zz[n][r] = fmaf(ak, tn[r], zz[n][r]);
        }
        tp[n] = tcu[n];
        tcu[n] = tn;
        if (k < NDEG) {
#pragma unroll
          for (int r = 0; r < 4; ++r) {
            int row = 16 * wv + 4 * l16 + r, col = 16 * n + l15;
            writePair(dH, dL, row * 36 + (col >> 1), tn[r], lane);
          }
        }
      }
    }
    if (k < NDEG) __syncthreads();
  }
  __syncthreads();   // Cheb LDS dead -> red overlay allowed

  // ================= classifier (waves 0-3 hold zz) =================
  if (wv < 4) {
    float po[4] = {0.f, 0.f, 0.f, 0.f};
#pragma unroll
    for (int n = 0; n < 4; ++n)
#pragma unroll
      for (int r = 0; r < 4; ++r) {
        int i = 16 * wv + 4 * l16 + r, j = 16 * n + l15;
        const float zv = zz[n][r];
        const int base = i * 64 + j;
#pragma unroll
        for (int o = 0; o < 4; ++o)
          po[o] = fmaf(zv, lin_w[o * 4096 + base], po[o]);
      }
#pragma unroll
    for (int o = 0; o < 4; ++o) sm.r.red[tid][o] = po[o];
  }
  __syncthreads();
  if (tid < 64) {
    const int g = tid >> 4, li = tid & 15;
    float s = 0.f;
#pragma unroll
    for (int q = 0; q < 16; ++q) s += sm.r.red[li + 16 * q][g];
#pragma unroll
    for (int d = 8; d >= 1; d >>= 1) s += __shfl_down(s, d);
    if (li == 0) out[b * 4 + g] = s + lin_b[g];
  }
}

extern "C" void kernel_launch(void* const* d_in, const int* in_sizes, int n_in,
                              void* d_out, int out_size, void* d_ws, size_t ws_size,
                              hipStream_t stream) {
  const float* X     = (const float*)d_in[0];
  const float* W     = (const float*)d_in[1];
  const float* lin_w = (const float*)d_in[2];
  const float* lin_b = (const float*)d_in[3];
  float* out = (float*)d_out;
  spdnet_fused8_kernel<<<512, 512, 0, stream>>>(X, W, lin_w, lin_b, out);
}

// Round 11
// 75.717 us; speedup vs baseline: 2.2349x; 2.2349x over previous
//
#include <hip/hip_runtime.h>
#include <math.h>

#define NDEG 12

typedef unsigned short u16;
typedef unsigned int u32;
typedef _Float16 f16;
typedef __attribute__((ext_vector_type(8))) _Float16 f16x8;
typedef __attribute__((ext_vector_type(8))) short bf16x8;
typedef __attribute__((ext_vector_type(4))) float f32x4;

#define MFMA_F16(a, b, c)  __builtin_amdgcn_mfma_f32_16x16x32_f16(a, b, c, 0, 0, 0)
#define MFMA_BF16(a, b, c) __builtin_amdgcn_mfma_f32_16x16x32_bf16(a, b, c, 0, 0, 0)

__device__ __forceinline__ u32 fbits(float x) { return __float_as_uint(x); }
__device__ __forceinline__ float fval(u32 u) { return __uint_as_float(u); }
__device__ __forceinline__ f32x4 zero4() {
  f32x4 z; z[0] = 0.f; z[1] = 0.f; z[2] = 0.f; z[3] = 0.f; return z;
}
__device__ __forceinline__ u16 f16bits(f16 x) { u16 u; __builtin_memcpy(&u, &x, 2); return u; }
__device__ __forceinline__ float f16tof(u16 u) { f16 h; __builtin_memcpy(&h, &u, 2); return (float)h; }

// bf16 hi (trunc) + bf16 lo (RNE remainder) split  [rounds 2-10 known-good]
__device__ __forceinline__ void split2(float x, u32& h, u32& l) {
  u32 u = fbits(x);
  h = u >> 16;
  float lo = x - fval(u & 0xFFFF0000u);
  u32 v = fbits(lo);
  l = (v + 0x7FFFu + ((v >> 16) & 1u)) >> 16;
}
__device__ __forceinline__ void writePair(u32* Hw, u32* Lw, int widx, float v, int lane) {
  float pv = __shfl_xor(v, 1);
  u32 hv, lv, hp, lp;
  split2(v, hv, lv);
  split2(pv, hp, lp);
  const bool even = (lane & 1) == 0;
  u32 word = even ? (hv | (hp << 16)) : (lp | (lv << 16));
  u32* base = even ? Hw : Lw;
  base[widx] = word;
}

struct CovPh { char buf[3][16384]; };                    // 3 x 64-t tiles [128][64] f16, swizzled
struct ProjPh { u16 Cov[128][136]; u16 Wt[64][136]; };   // 52224 B
struct ChebPh {
  u16 MH[64][72]; u16 ML[64][72];
  u16 TbH[2][64][72]; u16 TbL[2][64][72];
};                                                        // 55296 B
struct RedPh { float red[256][4]; };                      // 4096 B (overlays ChebPh when dead)
union SmemU { CovPh a; ProjPh p; ChebPh c; RedPh r; };
static_assert(sizeof(SmemU) <= 65536, "smem");

// 8-wave Gram split: flat upper-tri tile list for row-pair (W, 7-W):
// k=0..7-W: (W, W+k); k=8-W..8: (7-W, 7-W+(k-(8-W))). Wave 2W+H takes parity-H entries.
// Register-dieted: only 3 resident fragments; B-fragments loaded per-J on demand.
template <int W, int H>
__device__ __forceinline__ void gram8(const char* bufb, int fo0, int fo1,
                                      f32x4 (&acc)[5], f32x4& xs, f16x8 ones) {
  constexpr int I2 = 7 - W;
#pragma unroll
  for (int ch = 0; ch < 2; ++ch) {
    const int fo = ch ? fo1 : fo0;
    const f16x8 Fi1 = *(const f16x8*)(bufb + W * 2048 + fo);
    const f16x8 Fi2 = *(const f16x8*)(bufb + I2 * 2048 + fo);
    const f16x8 Fxs = *(const f16x8*)(bufb + (2 * W + H) * 2048 + fo);
#pragma unroll
    for (int k = 0; k < 9; ++k) {
      if ((k & 1) != H) continue;
      const int I = (k <= 7 - W) ? W : I2;
      const int J = (k <= 7 - W) ? (W + k) : (I2 + (k - (8 - W)));
      const f16x8 Fj = *(const f16x8*)(bufb + J * 2048 + fo);
      acc[k >> 1] = MFMA_F16((I == W) ? Fi1 : Fi2, Fj, acc[k >> 1]);
    }
    xs = MFMA_F16(Fxs, ones, xs);
  }
}

__device__ __forceinline__ void covTile(u16* Cov, const f32x4& v, int I, int J,
                                        int l15, int l16, bool mirror) {
#pragma unroll
  for (int r = 0; r < 4; ++r) {
    int row = 16 * I + 4 * l16 + r;
    int col = 16 * J + l15;
    u16 h = f16bits((f16)(v[r] * 1e-3f));
    Cov[row * 136 + col] = h;
    if (mirror) Cov[col * 136 + row] = h;
  }
}

template <int W, int H>
__device__ __forceinline__ void covStore8(u16* Cov, const f32x4 (&acc)[5], int l15, int l16) {
  constexpr int I2 = 7 - W;
#pragma unroll
  for (int k = 0; k < 9; ++k) {
    if ((k & 1) != H) continue;
    const int I = (k <= 7 - W) ? W : I2;
    const int J = (k <= 7 - W) ? (W + k) : (I2 + (k - (8 - W)));
    covTile(Cov, acc[k >> 1], I, J, l15, l16, I != J);
  }
}

__global__ __launch_bounds__(512, 4) void spdnet_fused9_kernel(
    const float* __restrict__ X, const float* __restrict__ W,
    const float* __restrict__ lin_w, const float* __restrict__ lin_b,
    float* __restrict__ out)
{
  __shared__ SmemU sm;
  __shared__ float mwL[64];
  __shared__ float xsL[128];

  const int tid = threadIdx.x;           // 0..511
  const int lane = tid & 63;
  const int wv = tid >> 6;               // 0..7
  const int l15 = lane & 15;
  const int l16 = lane >> 4;             // 0..3
  const int b = blockIdx.x;
  const char* __restrict__ Xbc = (const char*)(X + (size_t)b * 128000u);

  // ================= phase A: Cov = X X^T, f16 MFMA, 8-wave symmetric split =========
  // 16 tiles of 64 t. instr q: row rq = 16wv + 4q + l16; l15 sweeps 16 x 16-B chunks.
  int goff[4], lb[4];
#pragma unroll
  for (int q = 0; q < 4; ++q) {
    const int rq = 16 * wv + 4 * q + l16;
    goff[q] = rq * 4000 + l15 * 16;                       // byte offset of (row, t=4*l15)
    lb[q] = rq * 128 + ((l15 * 8) ^ ((rq & 7) << 4));     // f16 tile byte addr (swizzled)
  }
  const int swz = (l15 & 7) << 4;
  const int fo0 = l15 * 128 + ((16 * l16) ^ swz);         // frag read, ch 0
  const int fo1 = l15 * 128 + ((16 * l16 + 64) ^ swz);    // frag read, ch 1

  f16x8 ones;
#pragma unroll
  for (int i = 0; i < 8; ++i) ones[i] = (f16)1.0f;

  f32x4 acc[5];
#pragma unroll
  for (int u = 0; u < 5; ++u) acc[u] = zero4();
  f32x4 xs = zero4();

  // two STATICALLY-NAMED register tile buffers (4 float4 each; static idx only)
  float4 ldA[4], ldB[4];

#define L4(ld, tile)                                              \
  do {                                                            \
    _Pragma("unroll")                                             \
    for (int q = 0; q < 4; ++q)                                   \
      ld[q] = *(const float4*)(Xbc + goff[q] + (tile) * 256);     \
  } while (0)
#define L4_TAIL(ld)                                               \
  do {                                                            \
    const bool valid = l15 < 10;                                  \
    const int off = valid ? 3840 : (3984 - l15 * 16);             \
    _Pragma("unroll")                                             \
    for (int q = 0; q < 4; ++q) {                                 \
      float4 v = *(const float4*)(Xbc + goff[q] + off);           \
      ld[q] = valid ? v : make_float4(0.f, 0.f, 0.f, 0.f);        \
    }                                                             \
  } while (0)
#define S4(bi, ld)                                                \
  do {                                                            \
    char* rb_ = sm.a.buf[bi];                                     \
    _Pragma("unroll")                                             \
    for (int q = 0; q < 4; ++q) {                                 \
      u32 w0 = (u32)f16bits((f16)ld[q].x) | ((u32)f16bits((f16)ld[q].y) << 16); \
      u32 w1 = (u32)f16bits((f16)ld[q].z) | ((u32)f16bits((f16)ld[q].w) << 16); \
      uint2 wr; wr.x = w0; wr.y = w1;                             \
      *(uint2*)(rb_ + lb[q]) = wr;                                \
    }                                                             \
  } while (0)

  auto GRAM = [&](const char* rb) {
    switch (wv) {
      case 0: gram8<0,0>(rb, fo0, fo1, acc, xs, ones); break;
      case 1: gram8<0,1>(rb, fo0, fo1, acc, xs, ones); break;
      case 2: gram8<1,0>(rb, fo0, fo1, acc, xs, ones); break;
      case 3: gram8<1,1>(rb, fo0, fo1, acc, xs, ones); break;
      case 4: gram8<2,0>(rb, fo0, fo1, acc, xs, ones); break;
      case 5: gram8<2,1>(rb, fo0, fo1, acc, xs, ones); break;
      case 6: gram8<3,0>(rb, fo0, fo1, acc, xs, ones); break;
      default: gram8<3,1>(rb, fo0, fo1, acc, xs, ones); break;
    }
  };

  // prologue: tiles 0 (ldA), 1 (ldB) in flight; counted wait -> tile 0 ready; stage it
  L4(ldA, 0);
  L4(ldB, 1);
  asm volatile("s_waitcnt vmcnt(4)" ::: "memory");
  S4(0, ldA);
  asm volatile("s_waitcnt lgkmcnt(0)" ::: "memory");
  __builtin_amdgcn_s_barrier();

  // depth-2 pipeline at tile granularity; tile k in ldA if k even, ldB if odd;
  // LDS ring buf[k%3]. vmcnt(4) keeps the next tile's loads in flight across
  // every barrier; vmcnt(0) only at the tail.
  for (int h = 0; h < 8; ++h) {
    // ---- even tile t = 2h ----
    if (h < 7) L4(ldA, 2 * h + 2);
    GRAM(sm.a.buf[(2 * h) % 3]);
    if (h < 7) asm volatile("s_waitcnt vmcnt(4)" ::: "memory");
    else       asm volatile("s_waitcnt vmcnt(0)" ::: "memory");
    S4((2 * h + 1) % 3, ldB);            // stage tile 2h+1
    asm volatile("s_waitcnt lgkmcnt(0)" ::: "memory");
    __builtin_amdgcn_s_barrier();
    // ---- odd tile t = 2h+1 ----
    if (h < 6) L4(ldB, 2 * h + 3);
    else if (h == 6) L4_TAIL(ldB);       // tile 15 (t=960..1023, zero-pad >=1000)
    GRAM(sm.a.buf[(2 * h + 1) % 3]);
    if (h < 7) {
      asm volatile("s_waitcnt vmcnt(4)" ::: "memory");
      S4((2 * h + 2) % 3, ldA);          // stage tile 2h+2
      asm volatile("s_waitcnt lgkmcnt(0)" ::: "memory");
      __builtin_amdgcn_s_barrier();
    }
  }
#undef L4
#undef L4_TAIL
#undef S4

  // row sums from ones-MFMA (cols duplicated -> l15==0 lanes); wave covers rows 16wv..
  if (l15 == 0) {
#pragma unroll
    for (int r = 0; r < 4; ++r) xsL[16 * wv + 4 * l16 + r] = xs[r];
  }
  __syncthreads();   // phase-A LDS reads done -> overlay allowed

  // ================= phase P: materialize Cov (f16, *1e-3) + Wt =================
  {
    u16* CovP = &sm.p.Cov[0][0];
    switch (wv) {
      case 0: covStore8<0,0>(CovP, acc, l15, l16); break;
      case 1: covStore8<0,1>(CovP, acc, l15, l16); break;
      case 2: covStore8<1,0>(CovP, acc, l15, l16); break;
      case 3: covStore8<1,1>(CovP, acc, l15, l16); break;
      case 4: covStore8<2,0>(CovP, acc, l15, l16); break;
      case 5: covStore8<2,1>(CovP, acc, l15, l16); break;
      case 6: covStore8<3,0>(CovP, acc, l15, l16); break;
      default: covStore8<3,1>(CovP, acc, l15, l16); break;
    }
    u16* WtP = &sm.p.Wt[0][0];
    const int c = tid & 127, dh = tid >> 7;               // dh 0..3
    const float4* wp = (const float4*)(W + c * 64 + 16 * dh);
#pragma unroll
    for (int q = 0; q < 4; ++q) {
      float4 v = wp[q];
      int d0 = 16 * dh + 4 * q;
      WtP[(d0    ) * 136 + c] = f16bits((f16)v.x);
      WtP[(d0 + 1) * 136 + c] = f16bits((f16)v.y);
      WtP[(d0 + 2) * 136 + c] = f16bits((f16)v.z);
      WtP[(d0 + 3) * 136 + c] = f16bits((f16)v.w);
    }
  }
  __syncthreads();

  // mw = W^T xsum * 1e-3 (first 64 threads; overlaps P MFMA elsewhere)
  if (tid < 64) {
    float s = 0.f;
    for (int c = 0; c < 128; ++c)
      s = fmaf(f16tof(sm.p.Wt[tid][c]), xsL[c], s);
    mwL[tid] = s * 1.0e-3f;
  }

  // ---- P = Cov * W  (fp16 MFMA; wave wv owns rows 16wv..16wv+16) ----
  const u16* CovP = &sm.p.Cov[0][0];
  const u16* WtP  = &sm.p.Wt[0][0];
  f32x4 pAcc[4];
#pragma unroll
  for (int n = 0; n < 4; ++n) pAcc[n] = zero4();
#pragma unroll
  for (int ch = 0; ch < 4; ++ch) {
    f16x8 aC = *(const f16x8*)&CovP[(16 * wv + l15) * 136 + 8 * l16 + 32 * ch];
#pragma unroll
    for (int n = 0; n < 4; ++n) {
      f16x8 bw = *(const f16x8*)&WtP[(16 * n + l15) * 136 + 8 * l16 + 32 * ch];
      pAcc[n] = MFMA_F16(aC, bw, pAcc[n]);
    }
  }
  __syncthreads();   // Cov reads done -> Pt may overlay

  // ---- Pt[d][c] = P[c][d]  (fp16, overlays Cov) ----
  {
    u16* PtP = (u16*)&sm.p.Cov[0][0];
#pragma unroll
    for (int n = 0; n < 4; ++n)
#pragma unroll
      for (int r = 0; r < 4; ++r) {
        int c = 16 * wv + 4 * l16 + r;
        int d = 16 * n + l15;
        PtP[d * 136 + c] = f16bits((f16)pAcc[n][r]);
      }
  }
  __syncthreads();

  // ---- Y = W^T P  (waves 0..3 own d-rows 16wv..16wv+16) ----
  const u16* PtP = (const u16*)&sm.p.Cov[0][0];
  f32x4 yAcc[4];
#pragma unroll
  for (int n = 0; n < 4; ++n) yAcc[n] = zero4();
  if (wv < 4) {
#pragma unroll
    for (int ch = 0; ch < 4; ++ch) {
      f16x8 aW = *(const f16x8*)&WtP[(16 * wv + l15) * 136 + 8 * l16 + 32 * ch];
#pragma unroll
      for (int n = 0; n < 4; ++n) {
        f16x8 bP = *(const f16x8*)&PtP[(16 * n + l15) * 136 + 8 * l16 + 32 * ch];
        yAcc[n] = MFMA_F16(aW, bP, yAcc[n]);
      }
    }
  }
  __syncthreads();   // Wt/Pt dead -> Chebyshev planes may overlay

  // ================= phase C: M init + Chebyshev matrix-log (bf16 3-term, waves 0-3) ======
  const float CC = 1.125f;
  const float IH = 1.0f / 0.875f;
  const float uu = 0.875f / 1.125f;
  const float rho = (sqrtf(1.0f - uu * uu) - 1.0f) / uu;   // ~ -0.47759
  const float a0c = logf(CC / (1.0f + rho * rho));
  const float a1c = -2.0f * rho;

  f32x4 zz[4], tp[4], tcu[4];
  if (wv < 4) {
    u32* MHw = (u32*)&sm.c.MH[0][0];
    u32* MLw = (u32*)&sm.c.ML[0][0];
#pragma unroll
    for (int n = 0; n < 4; ++n)
#pragma unroll
      for (int r = 0; r < 4; ++r) {
        int i = 16 * wv + 4 * l16 + r, j = 16 * n + l15;
        float y = yAcc[n][r] - mwL[i] * mwL[j];
        float m = (y - ((i == j) ? CC : 0.f)) * IH;
        float e = (i == j) ? 1.f : 0.f;
        tp[n][r] = e;
        tcu[n][r] = m;
        zz[n][r] = a0c * e + a1c * m;
        writePair(MHw, MLw, i * 36 + (j >> 1), m, lane);
      }
  }
  __syncthreads();

  bf16x8 aMh[2], aMl[2];
  if (wv < 4) {
#pragma unroll
    for (int ch = 0; ch < 2; ++ch) {
      aMh[ch] = *(const bf16x8*)&sm.c.MH[16 * wv + l15][8 * l16 + 32 * ch];
      aMl[ch] = *(const bf16x8*)&sm.c.ML[16 * wv + l15][8 * l16 + 32 * ch];
    }
  }

  float rhok = rho;
  for (int k = 2; k <= NDEG; ++k) {
    rhok *= rho;
    const float ak = (-2.0f / (float)k) * rhok;
    if (wv < 4) {
      const u16 (*srcH)[72] = (k == 2) ? sm.c.MH : sm.c.TbH[(k - 1) & 1];
      const u16 (*srcL)[72] = (k == 2) ? sm.c.ML : sm.c.TbL[(k - 1) & 1];
      f32x4 p[4];
#pragma unroll
      for (int n = 0; n < 4; ++n) p[n] = zero4();
#pragma unroll
      for (int ch = 0; ch < 2; ++ch) {
#pragma unroll
        for (int n = 0; n < 4; ++n) {
          bf16x8 bh = *(const bf16x8*)&srcH[16 * n + l15][8 * l16 + 32 * ch];
          bf16x8 bl = *(const bf16x8*)&srcL[16 * n + l15][8 * l16 + 32 * ch];
          p[n] = MFMA_BF16(aMh[ch], bh, p[n]);
          p[n] = MFMA_BF16(aMh[ch], bl, p[n]);
          p[n] = MFMA_BF16(aMl[ch], bh, p[n]);
        }
      }
      u32* dH = (u32*)&sm.c.TbH[k & 1][0][0];
      u32* dL = (u32*)&sm.c.TbL[k & 1][0][0];
#pragma unroll
      for (int n = 0; n < 4; ++n) {
        f32x4 tn;
#pragma unroll
        for (int r = 0; r < 4; ++r) {
          tn[r] = 2.f * p[n][r] - tp[n][r];
          zz[n][r] = fmaf(ak, tn[r], zz[n][r]);
        }
        tp[n] = tcu[n];
        tcu[n] = tn;
        if (k < NDEG) {
#pragma unroll
          for (int r = 0; r < 4; ++r) {
            int row = 16 * wv + 4 * l16 + r, col = 16 * n + l15;
            writePair(dH, dL, row * 36 + (col >> 1), tn[r], lane);
          }
        }
      }
    }
    if (k < NDEG) __syncthreads();
  }
  __syncthreads();   // Cheb LDS dead -> red overlay allowed

  // ================= classifier (waves 0-3 hold zz) =================
  if (wv < 4) {
    float po[4] = {0.f, 0.f, 0.f, 0.f};
#pragma unroll
    for (int n = 0; n < 4; ++n)
#pragma unroll
      for (int r = 0; r < 4; ++r) {
        int i = 16 * wv + 4 * l16 + r, j = 16 * n + l15;
        const float zv = zz[n][r];
        const int base = i * 64 + j;
#pragma unroll
        for (int o = 0; o < 4; ++o)
          po[o] = fmaf(zv, lin_w[o * 4096 + base], po[o]);
      }
#pragma unroll
    for (int o = 0; o < 4; ++o) sm.r.red[tid][o] = po[o];
  }
  __syncthreads();
  if (tid < 64) {
    const int g = tid >> 4, li = tid & 15;
    float s = 0.f;
#pragma unroll
    for (int q = 0; q < 16; ++q) s += sm.r.red[li + 16 * q][g];
#pragma unroll
    for (int d = 8; d >= 1; d >>= 1) s += __shfl_down(s, d);
    if (li == 0) out[b * 4 + g] = s + lin_b[g];
  }
}

extern "C" void kernel_launch(void* const* d_in, const int* in_sizes, int n_in,
                              void* d_out, int out_size, void* d_ws, size_t ws_size,
                              hipStream_t stream) {
  const float* X     = (const float*)d_in[0];
  const float* W     = (const float*)d_in[1];
  const float* lin_w = (const float*)d_in[2];
  const float* lin_b = (const float*)d_in[3];
  float* out = (float*)d_out;
  spdnet_fused9_kernel<<<512, 512, 0, stream>>>(X, W, lin_w, lin_b, out);
}